// Round 1
// baseline (8623.244 us; speedup 1.0000x reference)
//
#include <hip/hip_runtime.h>
#include <hip/hip_bf16.h>
#include <cstdint>
#include <cstddef>

#define IN_CH 312
#define HID 256

// ---------------------------------------------------------------------------
// Index dtype detector: edge_index is int64 in the reference, but the harness
// contract says integer inputs may arrive as int32. int64 values < 2^31 in
// little-endian have zero high words; random int32 edge data cannot have 64
// consecutive zero odd-words. Writes flag=1 if data is int64.
// ---------------------------------------------------------------------------
__global__ void detect_idx_kernel(const void* __restrict__ ei, int* __restrict__ flag) {
    if (blockIdx.x == 0 && threadIdx.x == 0) {
        const int* p = (const int*)ei;
        int ok = 1;
        for (int i = 0; i < 64; ++i) ok &= (p[2 * i + 1] == 0);
        *flag = ok;
    }
}

__device__ __forceinline__ long long load_idx(const void* ei, long long i, bool is64) {
    return is64 ? ((const long long*)ei)[i] : (long long)((const int*)ei)[i];
}

// ---------------------------------------------------------------------------
// Degree histogram: deg[dst] += 1 per edge.
// ---------------------------------------------------------------------------
__global__ void deg_kernel(const void* __restrict__ ei, const int* __restrict__ flag,
                           float* __restrict__ deg, int E) {
    const int i = blockIdx.x * blockDim.x + threadIdx.x;
    if (i >= E) return;
    const bool is64 = (*flag != 0);
    const long long d = load_idx(ei, (long long)E + i, is64);
    atomicAdd(&deg[d], 1.0f);
}

// ---------------------------------------------------------------------------
// Scatter-add aggregation: AGG[dst,:] += X[src,:]. One wave per edge; lane l
// handles float4 chunks at columns l*4, l*4+256, ... (covers C=256 and C=312).
// ---------------------------------------------------------------------------
__global__ void scatter_add_kernel(const void* __restrict__ ei, const int* __restrict__ flag,
                                   const float* __restrict__ X, float* __restrict__ AGG,
                                   int E, int C) {
    const int lane = threadIdx.x & 63;
    const int gw = (int)((blockIdx.x * (long long)blockDim.x + threadIdx.x) >> 6);
    const int nw = (int)(((long long)gridDim.x * blockDim.x) >> 6);
    const bool is64 = (*flag != 0);
    for (int e = gw; e < E; e += nw) {
        const long long s = load_idx(ei, e, is64);
        const long long d = load_idx(ei, (long long)E + e, is64);
        const float* xr = X + (size_t)s * C;
        float* ar = AGG + (size_t)d * C;
        for (int c = lane * 4; c < C; c += 256) {
            const float4 v = *(const float4*)(xr + c);
            atomicAdd(ar + c + 0, v.x);
            atomicAdd(ar + c + 1, v.y);
            atomicAdd(ar + c + 2, v.z);
            atomicAdd(ar + c + 3, v.w);
        }
    }
}

// ---------------------------------------------------------------------------
// Fused SAGE GEMM: C[i,:] = (Aagg[i,:]/max(deg[i],1)) @ Wl + Aself[i,:] @ Wr
//                           + bias  (+ ReLU)
// Block: 256 threads, tile 64 rows x 256 cols (full width). Per-thread 16x4
// micro-tile. A staged in LDS (inner reads are wave-broadcast, conflict-free;
// +4 pad spreads write banks). W rows streamed from global (L2-resident,
// <=320 KB, shared by all blocks).
// Full-width tile => each A row is read by exactly ONE block, and all reads
// precede that block's C stores => C may alias Aself (in-place layer 2).
// ---------------------------------------------------------------------------
template <bool RELU>
__global__ __launch_bounds__(256) void sage_gemm_kernel(
    const float* __restrict__ Aagg,   // [M,K1]
    const float* __restrict__ Aself,  // [M,K2]
    const float* __restrict__ Wl,     // [K1,256]
    const float* __restrict__ Wr,     // [K2,256]
    const float* __restrict__ bias,   // [256]
    const float* __restrict__ deg,    // [M]
    float* __restrict__ C,            // [M,256]
    int M, int K1, int K2)
{
    __shared__ float a_lds[64][68];   // 68: pad to spread write banks, keeps 16B align
    __shared__ float sdeg[64];

    const int r0    = blockIdx.x * 64;
    const int lane  = threadIdx.x & 63;
    const int wave  = threadIdx.x >> 6;
    const int c4    = lane * 4;
    const int rbase = wave * 16;

    if (threadIdx.x < 64) {
        const int gr = r0 + threadIdx.x;
        const float dg = (gr < M) ? deg[gr] : 1.0f;
        sdeg[threadIdx.x] = 1.0f / fmaxf(dg, 1.0f);
    }

    float4 acc[16];
    #pragma unroll
    for (int r = 0; r < 16; ++r) acc[r] = make_float4(0.f, 0.f, 0.f, 0.f);

    #pragma unroll
    for (int seg = 0; seg < 2; ++seg) {
        const float* __restrict__ A = seg ? Aself : Aagg;
        const float* __restrict__ W = seg ? Wr : Wl;
        const int K = seg ? K2 : K1;

        for (int kb = 0; kb < K; kb += 64) {
            const int kmax = (K - kb < 64) ? (K - kb) : 64;
            __syncthreads();  // also covers sdeg on first iteration
            // stage 64x64 A tile (K is a multiple of 4, so float4 never straddles K)
            #pragma unroll 4
            for (int idx = threadIdx.x; idx < 1024; idx += 256) {
                const int row = idx >> 4;
                const int ch  = (idx & 15) * 4;
                const int gr  = r0 + row;
                const int gc  = kb + ch;
                float4 v = make_float4(0.f, 0.f, 0.f, 0.f);
                if (gr < M && gc < K)
                    v = *(const float4*)(A + (size_t)gr * K + gc);
                if (seg == 0) {
                    const float sc = sdeg[row];
                    v.x *= sc; v.y *= sc; v.z *= sc; v.w *= sc;
                }
                *(float4*)&a_lds[row][ch] = v;
            }
            __syncthreads();

            const float* wp = W + (size_t)kb * 256 + c4;
            auto mma_step = [&](int kk) {
                const float4 w = *(const float4*)(wp + (size_t)kk * 256);
                #pragma unroll
                for (int r = 0; r < 16; ++r) {
                    const float a = a_lds[rbase + r][kk];
                    acc[r].x = fmaf(a, w.x, acc[r].x);
                    acc[r].y = fmaf(a, w.y, acc[r].y);
                    acc[r].z = fmaf(a, w.z, acc[r].z);
                    acc[r].w = fmaf(a, w.w, acc[r].w);
                }
            };
            if (kmax == 64) {
                #pragma unroll 4
                for (int kk = 0; kk < 64; ++kk) mma_step(kk);
            } else {
                for (int kk = 0; kk < kmax; ++kk) mma_step(kk);
            }
        }
    }

    const float4 b = *(const float4*)(bias + c4);
    #pragma unroll
    for (int r = 0; r < 16; ++r) {
        const int row = r0 + rbase + r;
        if (row < M) {
            float4 o;
            o.x = acc[r].x + b.x;
            o.y = acc[r].y + b.y;
            o.z = acc[r].z + b.z;
            o.w = acc[r].w + b.w;
            if (RELU) {
                o.x = fmaxf(o.x, 0.f); o.y = fmaxf(o.y, 0.f);
                o.z = fmaxf(o.z, 0.f); o.w = fmaxf(o.w, 0.f);
            }
            *(float4*)(C + (size_t)row * 256 + c4) = o;
        }
    }
}

// ---------------------------------------------------------------------------
extern "C" void kernel_launch(void* const* d_in, const int* in_sizes, int n_in,
                              void* d_out, int out_size, void* d_ws, size_t ws_size,
                              hipStream_t stream) {
    const float* x   = (const float*)d_in[0];
    const void*  ei  = d_in[1];
    const float* W1l = (const float*)d_in[2];
    const float* b1  = (const float*)d_in[3];
    const float* W1r = (const float*)d_in[4];
    const float* W2l = (const float*)d_in[5];
    const float* b2  = (const float*)d_in[6];
    const float* W2r = (const float*)d_in[7];

    const int N = in_sizes[0] / IN_CH;  // 100000
    const int E = in_sizes[1] / 2;      // 1000000

    // workspace layout: deg [N f32] | flag [int] | agg [N*312 f32]
    char* ws = (char*)d_ws;
    size_t off = 0;
    float* deg = (float*)(ws + off);
    off += (size_t)N * 4; off = (off + 255) & ~(size_t)255;
    int* flag = (int*)(ws + off);
    off += 256;
    float* agg = (float*)(ws + off);

    float* h = (float*)d_out;  // layer-1 output lives in d_out

    hipMemsetAsync(deg, 0, (size_t)N * 4, stream);
    hipMemsetAsync(agg, 0, (size_t)N * IN_CH * 4, stream);
    detect_idx_kernel<<<1, 64, 0, stream>>>(ei, flag);
    deg_kernel<<<(E + 255) / 256, 256, 0, stream>>>(ei, flag, deg, E);

    // ---- layer 1 ----
    scatter_add_kernel<<<(E + 3) / 4, 256, 0, stream>>>(ei, flag, x, agg, E, IN_CH);
    sage_gemm_kernel<true><<<(N + 63) / 64, 256, 0, stream>>>(
        agg, x, W1l, W1r, b1, deg, h, N, IN_CH, IN_CH);

    // ---- layer 2 ----
    hipMemsetAsync(agg, 0, (size_t)N * HID * 4, stream);
    scatter_add_kernel<<<(E + 3) / 4, 256, 0, stream>>>(ei, flag, h, agg, E, HID);
    sage_gemm_kernel<false><<<(N + 63) / 64, 256, 0, stream>>>(
        agg, h, W2l, W2r, b2, deg, (float*)d_out, N, HID, HID);
}

// Round 2
// 1445.249 us; speedup vs baseline: 5.9666x; 5.9666x over previous
//
#include <hip/hip_runtime.h>
#include <hip/hip_bf16.h>
#include <cstdint>
#include <cstddef>

#define IN_CH 312
#define HID 256

// ---------------------------------------------------------------------------
// Index dtype detector: reference uses int64 edge_index; harness may hand us
// int32. int64 values < 2^31 have zero high words in little-endian.
// ---------------------------------------------------------------------------
__global__ void detect_idx_kernel(const void* __restrict__ ei, int* __restrict__ flag) {
    if (blockIdx.x == 0 && threadIdx.x == 0) {
        const int* p = (const int*)ei;
        int ok = 1;
        for (int i = 0; i < 64; ++i) ok &= (p[2 * i + 1] == 0);
        *flag = ok;
    }
}

__device__ __forceinline__ long long load_idx(const void* ei, long long i, bool is64) {
    return is64 ? ((const long long*)ei)[i] : (long long)((const int*)ei)[i];
}

// ---------------------------------------------------------------------------
// CSR build: histogram of dst, exclusive scan, fill with atomic cursors.
// ---------------------------------------------------------------------------
__global__ void hist_kernel(const void* __restrict__ ei, const int* __restrict__ flag,
                            int* __restrict__ cnt, int E) {
    const int i = blockIdx.x * blockDim.x + threadIdx.x;
    if (i >= E) return;
    const bool is64 = (*flag != 0);
    const long long d = load_idx(ei, (long long)E + i, is64);
    atomicAdd(&cnt[d], 1);
}

__global__ __launch_bounds__(1024) void scan_kernel(const int* __restrict__ cnt,
                                                    int* __restrict__ row_ptr, int n) {
    __shared__ int buf[1024];
    __shared__ int carry_s;
    const int t = threadIdx.x;
    if (t == 0) carry_s = 0;
    __syncthreads();
    for (int base = 0; base < n; base += 1024) {
        const int v = (base + t < n) ? cnt[base + t] : 0;
        buf[t] = v;
        __syncthreads();
        #pragma unroll
        for (int off = 1; off < 1024; off <<= 1) {
            const int add = (t >= off) ? buf[t - off] : 0;
            __syncthreads();
            buf[t] += add;
            __syncthreads();
        }
        const int incl = buf[t];
        const int carry = carry_s;
        if (base + t < n) row_ptr[base + t] = carry + incl - v;  // exclusive
        __syncthreads();
        if (t == 1023) carry_s = carry + incl;
        __syncthreads();
    }
    if (t == 0) row_ptr[n] = carry_s;
}

__global__ void fill_kernel(const void* __restrict__ ei, const int* __restrict__ flag,
                            int* __restrict__ cur, int* __restrict__ col, int E) {
    const int i = blockIdx.x * blockDim.x + threadIdx.x;
    if (i >= E) return;
    const bool is64 = (*flag != 0);
    const long long s = load_idx(ei, i, is64);
    const long long d = load_idx(ei, (long long)E + i, is64);
    const int pos = atomicAdd(&cur[d], 1);
    col[pos] = (int)s;
}

// ---------------------------------------------------------------------------
// Dual GEMM: Y[i,:] = A[i,:] @ Wl ; Z[i,:] = A[i,:] @ Wr + bias.
// 512 threads (8 waves), tile 64 rows x 256 cols. Per-thread: 8 rows x 4 cols
// x 2 outputs = 16 float4 accs. A staged in LDS (inner reads wave-broadcast).
// Z may alias A (row-block reads all precede its writes; barrier-ordered).
// ---------------------------------------------------------------------------
__global__ __launch_bounds__(512) void dual_gemm_kernel(
    const float* A, const float* __restrict__ Wl, const float* __restrict__ Wr,
    const float* __restrict__ bias, float* __restrict__ Y, float* Z, int M, int K)
{
    __shared__ float a_lds[64][68];
    const int r0    = blockIdx.x * 64;
    const int lane  = threadIdx.x & 63;
    const int wave  = threadIdx.x >> 6;
    const int c4    = lane * 4;
    const int rbase = wave * 8;

    float4 accl[8], accr[8];
    #pragma unroll
    for (int r = 0; r < 8; ++r) {
        accl[r] = make_float4(0.f, 0.f, 0.f, 0.f);
        accr[r] = make_float4(0.f, 0.f, 0.f, 0.f);
    }

    for (int kb = 0; kb < K; kb += 64) {
        const int kmax = (K - kb < 64) ? (K - kb) : 64;
        __syncthreads();
        #pragma unroll 2
        for (int idx = threadIdx.x; idx < 1024; idx += 512) {
            const int row = idx >> 4;
            const int ch  = (idx & 15) * 4;
            const int gr  = r0 + row;
            const int gc  = kb + ch;
            float4 v = make_float4(0.f, 0.f, 0.f, 0.f);
            if (gr < M && gc < K)
                v = *(const float4*)(A + (size_t)gr * K + gc);
            *(float4*)&a_lds[row][ch] = v;
        }
        __syncthreads();

        const float* wlp = Wl + (size_t)kb * 256 + c4;
        const float* wrp = Wr + (size_t)kb * 256 + c4;
        auto mma_step = [&](int kk) {
            const float4 wl = *(const float4*)(wlp + (size_t)kk * 256);
            const float4 wr = *(const float4*)(wrp + (size_t)kk * 256);
            #pragma unroll
            for (int r = 0; r < 8; ++r) {
                const float a = a_lds[rbase + r][kk];
                accl[r].x = fmaf(a, wl.x, accl[r].x);
                accl[r].y = fmaf(a, wl.y, accl[r].y);
                accl[r].z = fmaf(a, wl.z, accl[r].z);
                accl[r].w = fmaf(a, wl.w, accl[r].w);
                accr[r].x = fmaf(a, wr.x, accr[r].x);
                accr[r].y = fmaf(a, wr.y, accr[r].y);
                accr[r].z = fmaf(a, wr.z, accr[r].z);
                accr[r].w = fmaf(a, wr.w, accr[r].w);
            }
        };
        if (kmax == 64) {
            #pragma unroll 4
            for (int kk = 0; kk < 64; ++kk) mma_step(kk);
        } else {
            for (int kk = 0; kk < kmax; ++kk) mma_step(kk);
        }
    }

    const float4 b = *(const float4*)(bias + c4);
    #pragma unroll
    for (int r = 0; r < 8; ++r) {
        const int row = r0 + rbase + r;
        if (row < M) {
            *(float4*)(Y + (size_t)row * 256 + c4) = accl[r];
            float4 o;
            o.x = accr[r].x + b.x;
            o.y = accr[r].y + b.y;
            o.z = accr[r].z + b.z;
            o.w = accr[r].w + b.w;
            *(float4*)(Z + (size_t)row * 256 + c4) = o;
        }
    }
}

// ---------------------------------------------------------------------------
// Gather aggregation: OUT[i,:] = relu?( (sum_{e in CSR[i]} Y[col[e],:]) / deg
//                                       + OUT[i,:] )        (OUT holds Z)
// One wave per node; lane l owns channels 4l..4l+3 (C=256 exactly).
// ---------------------------------------------------------------------------
template <bool RELU>
__global__ void gather_agg_kernel(const float* __restrict__ Y,
                                  const int* __restrict__ row_ptr,
                                  const int* __restrict__ col,
                                  float* __restrict__ OUT, int N)
{
    const int w = (int)(((long long)blockIdx.x * blockDim.x + threadIdx.x) >> 6);
    const int lane = threadIdx.x & 63;
    if (w >= N) return;
    const int beg = row_ptr[w];
    const int end = row_ptr[w + 1];
    const int c4 = lane * 4;

    float4 acc = make_float4(0.f, 0.f, 0.f, 0.f);
    int e = beg;
    for (; e + 1 < end; e += 2) {
        const int s0 = col[e];
        const int s1 = col[e + 1];
        const float4 v0 = *(const float4*)(Y + (size_t)s0 * 256 + c4);
        const float4 v1 = *(const float4*)(Y + (size_t)s1 * 256 + c4);
        acc.x += v0.x + v1.x;
        acc.y += v0.y + v1.y;
        acc.z += v0.z + v1.z;
        acc.w += v0.w + v1.w;
    }
    if (e < end) {
        const int s0 = col[e];
        const float4 v0 = *(const float4*)(Y + (size_t)s0 * 256 + c4);
        acc.x += v0.x; acc.y += v0.y; acc.z += v0.z; acc.w += v0.w;
    }

    const float inv = 1.0f / fmaxf((float)(end - beg), 1.0f);
    float* op = OUT + (size_t)w * 256 + c4;
    const float4 z = *(const float4*)op;
    float4 o;
    o.x = acc.x * inv + z.x;
    o.y = acc.y * inv + z.y;
    o.z = acc.z * inv + z.z;
    o.w = acc.w * inv + z.w;
    if (RELU) {
        o.x = fmaxf(o.x, 0.f); o.y = fmaxf(o.y, 0.f);
        o.z = fmaxf(o.z, 0.f); o.w = fmaxf(o.w, 0.f);
    }
    *(float4*)op = o;
}

// ---------------------------------------------------------------------------
extern "C" void kernel_launch(void* const* d_in, const int* in_sizes, int n_in,
                              void* d_out, int out_size, void* d_ws, size_t ws_size,
                              hipStream_t stream) {
    const float* x   = (const float*)d_in[0];
    const void*  ei  = d_in[1];
    const float* W1l = (const float*)d_in[2];
    const float* b1  = (const float*)d_in[3];
    const float* W1r = (const float*)d_in[4];
    const float* W2l = (const float*)d_in[5];
    const float* b2  = (const float*)d_in[6];
    const float* W2r = (const float*)d_in[7];

    const int N = in_sizes[0] / IN_CH;  // 100000
    const int E = in_sizes[1] / 2;      // 1000000

    // workspace: flag | row_ptr[N+1] | cnt[N] | cur[N] | col[E] | y[N*256]
    char* ws = (char*)d_ws;
    size_t off = 0;
    int* flag = (int*)(ws + off);            off += 256;
    int* row_ptr = (int*)(ws + off);         off += ((size_t)(N + 1) * 4 + 255) & ~(size_t)255;
    int* cnt = (int*)(ws + off);             off += ((size_t)N * 4 + 255) & ~(size_t)255;
    int* cur = (int*)(ws + off);             off += ((size_t)N * 4 + 255) & ~(size_t)255;
    int* col = (int*)(ws + off);             off += ((size_t)E * 4 + 255) & ~(size_t)255;
    float* y = (float*)(ws + off);           // N*256 floats

    float* out = (float*)d_out;

    // ---- CSR build (by dst) ----
    hipMemsetAsync(cnt, 0, (size_t)N * 4, stream);
    detect_idx_kernel<<<1, 64, 0, stream>>>(ei, flag);
    hist_kernel<<<(E + 255) / 256, 256, 0, stream>>>(ei, flag, cnt, E);
    scan_kernel<<<1, 1024, 0, stream>>>(cnt, row_ptr, N);
    hipMemcpyAsync(cur, row_ptr, (size_t)N * 4, hipMemcpyDeviceToDevice, stream);
    fill_kernel<<<(E + 255) / 256, 256, 0, stream>>>(ei, flag, cur, col, E);

    // ---- layer 1: y = x@W1l ; z(out) = x@W1r + b1 ; h = relu(gather(y)/deg + z) ----
    dual_gemm_kernel<<<(N + 63) / 64, 512, 0, stream>>>(x, W1l, W1r, b1, y, out, N, IN_CH);
    gather_agg_kernel<true><<<(N + 3) / 4, 256, 0, stream>>>(y, row_ptr, col, out, N);

    // ---- layer 2: y = h@W2l ; z(out,in-place) = h@W2r + b2 ; out = gather(y)/deg + z ----
    dual_gemm_kernel<<<(N + 63) / 64, 512, 0, stream>>>(out, W2l, W2r, b2, y, out, N, HID);
    gather_agg_kernel<false><<<(N + 3) / 4, 256, 0, stream>>>(y, row_ptr, col, out, N);
}

// Round 3
// 616.203 us; speedup vs baseline: 13.9942x; 2.3454x over previous
//
#include <hip/hip_runtime.h>
#include <hip/hip_bf16.h>
#include <cstdint>
#include <cstddef>

#define IN_CH 312
#define HID 256

typedef __attribute__((ext_vector_type(8))) short bf16x8;
typedef __attribute__((ext_vector_type(4))) float f32x4;
typedef __attribute__((ext_vector_type(8))) unsigned short ushort8;

__device__ __forceinline__ unsigned short f2bf(float f) {
    union { float f; unsigned u; } v; v.f = f;
    const unsigned r = v.u + 0x7FFFu + ((v.u >> 16) & 1u);  // RNE
    return (unsigned short)(r >> 16);
}
__device__ __forceinline__ float bf2f(unsigned short s) {
    union { unsigned u; float f; } v; v.u = (unsigned)s << 16;
    return v.f;
}
__device__ __forceinline__ void gload_lds16(const void* g, void* l) {
    __builtin_amdgcn_global_load_lds(
        (const __attribute__((address_space(1))) void*)g,
        (__attribute__((address_space(3))) void*)l, 16, 0, 0);
}

// ---------------------------------------------------------------------------
// Index dtype detector (int64 vs int32 edge_index).
// ---------------------------------------------------------------------------
__global__ void detect_idx_kernel(const void* __restrict__ ei, int* __restrict__ flag) {
    if (blockIdx.x == 0 && threadIdx.x == 0) {
        const int* p = (const int*)ei;
        int ok = 1;
        for (int i = 0; i < 64; ++i) ok &= (p[2 * i + 1] == 0);
        *flag = ok;
    }
}
__device__ __forceinline__ long long load_idx(const void* ei, long long i, bool is64) {
    return is64 ? ((const long long*)ei)[i] : (long long)((const int*)ei)[i];
}

// ---------------------------------------------------------------------------
// CSR build: histogram, single-block scan (8 elems/thread), atomic-cursor fill.
// ---------------------------------------------------------------------------
__global__ void hist_kernel(const void* __restrict__ ei, const int* __restrict__ flag,
                            int* __restrict__ cnt, int E) {
    const int i = blockIdx.x * blockDim.x + threadIdx.x;
    if (i >= E) return;
    const bool is64 = (*flag != 0);
    atomicAdd(&cnt[load_idx(ei, (long long)E + i, is64)], 1);
}

__global__ __launch_bounds__(1024) void scan_kernel(const int* __restrict__ cnt,
                                                    int* __restrict__ row_ptr, int n) {
    __shared__ int buf[1024];
    __shared__ int carry_s;
    const int t = threadIdx.x;
    if (t == 0) carry_s = 0;
    __syncthreads();
    for (int base = 0; base < n; base += 8192) {
        int v[8];
        int s = 0;
        #pragma unroll
        for (int j = 0; j < 8; ++j) {
            const int i = base + t * 8 + j;
            v[j] = (i < n) ? cnt[i] : 0;
            s += v[j];
        }
        buf[t] = s;
        __syncthreads();
        #pragma unroll
        for (int off = 1; off < 1024; off <<= 1) {
            const int add = (t >= off) ? buf[t - off] : 0;
            __syncthreads();
            buf[t] += add;
            __syncthreads();
        }
        int excl = carry_s + buf[t] - s;
        #pragma unroll
        for (int j = 0; j < 8; ++j) {
            const int i = base + t * 8 + j;
            if (i < n) row_ptr[i] = excl;
            excl += v[j];
        }
        __syncthreads();
        if (t == 1023) carry_s = carry_s + buf[1023];
        __syncthreads();
    }
    if (t == 0) row_ptr[n] = carry_s;
}

__global__ void fill_kernel(const void* __restrict__ ei, const int* __restrict__ flag,
                            int* __restrict__ cur, int* __restrict__ col, int E) {
    const int i = blockIdx.x * blockDim.x + threadIdx.x;
    if (i >= E) return;
    const bool is64 = (*flag != 0);
    const long long s = load_idx(ei, i, is64);
    const long long d = load_idx(ei, (long long)E + i, is64);
    col[atomicAdd(&cur[d], 1)] = (int)s;
}

// ---------------------------------------------------------------------------
// Conversions.
// x fp32 [N,312] -> bf16 [N,320] (cols 312..319 zero).
// ---------------------------------------------------------------------------
__global__ void convert_x_kernel(const float* __restrict__ x, unsigned short* __restrict__ xb,
                                 int N) {
    const int tid = blockIdx.x * blockDim.x + threadIdx.x;
    if (tid >= N * 40) return;
    const int row = tid / 40;
    const int c8 = (tid % 40) * 8;
    ushort8 o;
    if (c8 < IN_CH) {
        const float4 v0 = *(const float4*)(x + (size_t)row * IN_CH + c8);
        const float4 v1 = *(const float4*)(x + (size_t)row * IN_CH + c8 + 4);
        o[0] = f2bf(v0.x); o[1] = f2bf(v0.y); o[2] = f2bf(v0.z); o[3] = f2bf(v0.w);
        o[4] = f2bf(v1.x); o[5] = f2bf(v1.y); o[6] = f2bf(v1.z); o[7] = f2bf(v1.w);
    } else {
        o = (ushort8)0;
    }
    *(ushort8*)(xb + (size_t)row * 320 + c8) = o;
}

// WcatT[c][k] = (c<256 ? Wl[k][c] : Wr[k][c-256]), bf16, k >= K zero-padded.
__global__ void convert_w_kernel(const float* __restrict__ Wl, const float* __restrict__ Wr,
                                 unsigned short* __restrict__ wt, int K, int Kpad) {
    const int tid = blockIdx.x * blockDim.x + threadIdx.x;
    if (tid >= 512 * Kpad) return;
    const int c = tid / Kpad;
    const int k = tid % Kpad;
    float v = 0.f;
    if (k < K) v = (c < 256) ? Wl[(size_t)k * 256 + c] : Wr[(size_t)k * 256 + (c - 256)];
    wt[(size_t)c * Kpad + k] = f2bf(v);
}

// ---------------------------------------------------------------------------
// MFMA GEMM: [M,KPAD]bf16 x WcatT[512,KPAD]bf16 -> cols 0-255: Y bf16 (ws),
// cols 256-511: Z = . + bias fp32 (d_out).
// 128x128 tile, BK=64, 4 waves (2x2), 16x16x32 bf16 MFMA, fp32 accum.
// LDS tiles [128][64] staged with global_load_lds(16B); T2 XOR swizzle applied
// via pre-swizzled GLOBAL source (linear LDS dest) + swizzled ds_read (rule #21).
// ---------------------------------------------------------------------------
template <int KPAD>
__global__ __launch_bounds__(256) void mfma_gemm_kernel(
    const unsigned short* __restrict__ A,   // [M][KPAD]
    const unsigned short* __restrict__ WT,  // [512][KPAD]
    const float* __restrict__ bias,         // [256]
    unsigned short* __restrict__ Y,         // [M][256]
    float* __restrict__ Z,                  // [M][256]
    int M)
{
    __shared__ short a_lds[128 * 64];
    __shared__ short b_lds[128 * 64];

    const int lane = threadIdx.x & 63;
    const int wid  = threadIdx.x >> 6;
    const int wr = wid >> 1, wc = wid & 1;
    const int r0 = blockIdx.x * 128;
    const int c0 = blockIdx.y * 128;

    f32x4 acc[4][4];
    #pragma unroll
    for (int i = 0; i < 4; ++i)
        #pragma unroll
        for (int j = 0; j < 4; ++j) acc[i][j] = (f32x4)0.f;

    // staging geometry: 16 wave-loads of 1024B per tile; wave w does loads w*4..w*4+3.
    // lane l -> tile row = ld*8 + (l>>3), source chunk = (l&7) ^ (l>>3)  [row&7 == l>>3]
    const int ldrow  = lane >> 3;
    const int schunk = (lane & 7) ^ ldrow;

    for (int kb = 0; kb < KPAD; kb += 64) {
        __syncthreads();  // prev compute done before overwrite
        #pragma unroll
        for (int j = 0; j < 4; ++j) {
            const int ld = wid * 4 + j;
            const int trow = ld * 8 + ldrow;
            const int agr = min(r0 + trow, M - 1);
            gload_lds16(A + (size_t)agr * KPAD + kb + schunk * 8,
                        (char*)a_lds + ld * 1024);
            gload_lds16(WT + (size_t)(c0 + trow) * KPAD + kb + schunk * 8,
                        (char*)b_lds + ld * 1024);
        }
        __syncthreads();  // drains vmcnt: tiles visible

        #pragma unroll
        for (int ks = 0; ks < 2; ++ks) {
            bf16x8 af[4], bg[4];
            #pragma unroll
            for (int f = 0; f < 4; ++f) {
                const int arow = wr * 64 + f * 16 + (lane & 15);
                const int ach  = (ks * 4 + (lane >> 4)) ^ (arow & 7);
                af[f] = *(const bf16x8*)((const char*)a_lds + arow * 128 + ach * 16);
                const int brow = wc * 64 + f * 16 + (lane & 15);
                const int bch  = (ks * 4 + (lane >> 4)) ^ (brow & 7);
                bg[f] = *(const bf16x8*)((const char*)b_lds + brow * 128 + bch * 16);
            }
            #pragma unroll
            for (int fm = 0; fm < 4; ++fm)
                #pragma unroll
                for (int fn = 0; fn < 4; ++fn)
                    acc[fm][fn] = __builtin_amdgcn_mfma_f32_16x16x32_bf16(
                        af[fm], bg[fn], acc[fm][fn], 0, 0, 0);
        }
    }

    // epilogue: C/D layout col=lane&15, row=(lane>>4)*4+reg  [m89]
    const int rbase = r0 + wr * 64 + (lane >> 4) * 4;
    const int cbase = c0 + wc * 64 + (lane & 15);
    if (c0 < 256) {
        #pragma unroll
        for (int fm = 0; fm < 4; ++fm)
            #pragma unroll
            for (int fn = 0; fn < 4; ++fn) {
                const int gc = cbase + fn * 16;
                #pragma unroll
                for (int r = 0; r < 4; ++r) {
                    const int gr = rbase + fm * 16 + r;
                    if (gr < M) Y[(size_t)gr * 256 + gc] = f2bf(acc[fm][fn][r]);
                }
            }
    } else {
        #pragma unroll
        for (int fn = 0; fn < 4; ++fn) {
            const int gc = cbase + fn * 16 - 256;
            const float bv = bias[gc];
            #pragma unroll
            for (int fm = 0; fm < 4; ++fm)
                #pragma unroll
                for (int r = 0; r < 4; ++r) {
                    const int gr = rbase + fm * 16 + r;
                    if (gr < M) Z[(size_t)gr * 256 + gc] = acc[fm][fn][r] + bv;
                }
        }
    }
}

// ---------------------------------------------------------------------------
// Gather aggregation over bf16 y: out[i] = act( mean_{e}(y[col[e]]) + Z[i] ).
// LAYER1: act=relu, write bf16 h (ws). else: write fp32 d_out (Z aliases OUT).
// ---------------------------------------------------------------------------
template <bool LAYER1>
__global__ void gather_agg_kernel(const unsigned short* __restrict__ Y,
                                  const int* __restrict__ row_ptr,
                                  const int* __restrict__ col,
                                  const float* __restrict__ Z,
                                  void* __restrict__ OUT, int N)
{
    const long long gw = ((long long)blockIdx.x * blockDim.x + threadIdx.x) >> 6;
    if (gw >= N) return;
    const int w = (int)gw;
    const int lane = threadIdx.x & 63;
    const int c4 = lane * 4;
    const int beg = row_ptr[w], end = row_ptr[w + 1];

    float4 acc = make_float4(0.f, 0.f, 0.f, 0.f);
    int e = beg;
    for (; e + 1 < end; e += 2) {
        const int s0 = col[e], s1 = col[e + 1];
        const ushort4 v0 = *(const ushort4*)(Y + (size_t)s0 * 256 + c4);
        const ushort4 v1 = *(const ushort4*)(Y + (size_t)s1 * 256 + c4);
        acc.x += bf2f(v0.x) + bf2f(v1.x);
        acc.y += bf2f(v0.y) + bf2f(v1.y);
        acc.z += bf2f(v0.z) + bf2f(v1.z);
        acc.w += bf2f(v0.w) + bf2f(v1.w);
    }
    if (e < end) {
        const ushort4 v0 = *(const ushort4*)(Y + (size_t)col[e] * 256 + c4);
        acc.x += bf2f(v0.x); acc.y += bf2f(v0.y);
        acc.z += bf2f(v0.z); acc.w += bf2f(v0.w);
    }

    const float inv = 1.0f / fmaxf((float)(end - beg), 1.0f);
    const float4 z = *(const float4*)(Z + (size_t)w * 256 + c4);
    float4 o;
    o.x = acc.x * inv + z.x;
    o.y = acc.y * inv + z.y;
    o.z = acc.z * inv + z.z;
    o.w = acc.w * inv + z.w;
    if (LAYER1) {
        o.x = fmaxf(o.x, 0.f); o.y = fmaxf(o.y, 0.f);
        o.z = fmaxf(o.z, 0.f); o.w = fmaxf(o.w, 0.f);
        ushort4 ob;
        ob.x = f2bf(o.x); ob.y = f2bf(o.y); ob.z = f2bf(o.z); ob.w = f2bf(o.w);
        *(ushort4*)((unsigned short*)OUT + (size_t)w * 256 + c4) = ob;
    } else {
        *(float4*)((float*)OUT + (size_t)w * 256 + c4) = o;
    }
}

// ---------------------------------------------------------------------------
extern "C" void kernel_launch(void* const* d_in, const int* in_sizes, int n_in,
                              void* d_out, int out_size, void* d_ws, size_t ws_size,
                              hipStream_t stream) {
    const float* x   = (const float*)d_in[0];
    const void*  ei  = d_in[1];
    const float* W1l = (const float*)d_in[2];
    const float* b1  = (const float*)d_in[3];
    const float* W1r = (const float*)d_in[4];
    const float* W2l = (const float*)d_in[5];
    const float* b2  = (const float*)d_in[6];
    const float* W2r = (const float*)d_in[7];

    const int N = in_sizes[0] / IN_CH;  // 100000
    const int E = in_sizes[1] / 2;      // 1000000

    // ws: flag | row_ptr[N+1] | cnt[N] | cur[N] | col[E] | wt1 | wt2 | bufA | bufB
    char* ws = (char*)d_ws;
    size_t off = 0;
    auto alloc = [&](size_t bytes) {
        void* p = ws + off;
        off = (off + bytes + 255) & ~(size_t)255;
        return p;
    };
    int* flag    = (int*)alloc(4);
    int* row_ptr = (int*)alloc((size_t)(N + 1) * 4);
    int* cnt     = (int*)alloc((size_t)N * 4);
    int* cur     = (int*)alloc((size_t)N * 4);
    int* col     = (int*)alloc((size_t)E * 4);
    unsigned short* wt1 = (unsigned short*)alloc((size_t)512 * 320 * 2);
    unsigned short* wt2 = (unsigned short*)alloc((size_t)512 * 256 * 2);
    unsigned short* bufA = (unsigned short*)alloc((size_t)N * 320 * 2);  // x_bf16, later h_bf16
    unsigned short* y    = (unsigned short*)alloc((size_t)N * 256 * 2);  // bf16 y

    float* out = (float*)d_out;

    // ---- CSR build (by dst) ----
    hipMemsetAsync(cnt, 0, (size_t)N * 4, stream);
    detect_idx_kernel<<<1, 64, 0, stream>>>(ei, flag);
    hist_kernel<<<(E + 255) / 256, 256, 0, stream>>>(ei, flag, cnt, E);
    scan_kernel<<<1, 1024, 0, stream>>>(cnt, row_ptr, N);
    hipMemcpyAsync(cur, row_ptr, (size_t)N * 4, hipMemcpyDeviceToDevice, stream);
    fill_kernel<<<(E + 255) / 256, 256, 0, stream>>>(ei, flag, cur, col, E);

    // ---- conversions ----
    convert_x_kernel<<<(N * 40 + 255) / 256, 256, 0, stream>>>(x, bufA, N);
    convert_w_kernel<<<(512 * 320 + 255) / 256, 256, 0, stream>>>(W1l, W1r, wt1, IN_CH, 320);
    convert_w_kernel<<<(512 * 256 + 255) / 256, 256, 0, stream>>>(W2l, W2r, wt2, HID, 256);

    const dim3 ggrid((N + 127) / 128, 4);

    // ---- layer 1: y=x@W1l (bf16), z(out)=x@W1r+b1 ; h(bufA)=relu(mean+z) ----
    mfma_gemm_kernel<320><<<ggrid, 256, 0, stream>>>(bufA, wt1, b1, y, out, N);
    gather_agg_kernel<true><<<(N + 3) / 4, 256, 0, stream>>>(y, row_ptr, col, out, bufA, N);

    // ---- layer 2: y=h@W2l, z(out)=h@W2r+b2 ; out = mean+z ----
    mfma_gemm_kernel<256><<<ggrid, 256, 0, stream>>>(bufA, wt2, b2, y, out, N);
    gather_agg_kernel<false><<<(N + 3) / 4, 256, 0, stream>>>(y, row_ptr, col, out, out, N);
}

// Round 4
// 535.679 us; speedup vs baseline: 16.0978x; 1.1503x over previous
//
#include <hip/hip_runtime.h>
#include <hip/hip_bf16.h>
#include <cstdint>
#include <cstddef>

#define IN_CH 312
#define HID 256

typedef __attribute__((ext_vector_type(8))) short bf16x8;
typedef __attribute__((ext_vector_type(4))) float f32x4;
typedef __attribute__((ext_vector_type(8))) unsigned short ushort8;

__device__ __forceinline__ unsigned short f2bf(float f) {
    union { float f; unsigned u; } v; v.f = f;
    const unsigned r = v.u + 0x7FFFu + ((v.u >> 16) & 1u);  // RNE
    return (unsigned short)(r >> 16);
}
__device__ __forceinline__ float bf2f(unsigned short s) {
    union { unsigned u; float f; } v; v.u = (unsigned)s << 16;
    return v.f;
}
__device__ __forceinline__ void gload_lds16(const void* g, void* l) {
    __builtin_amdgcn_global_load_lds(
        (const __attribute__((address_space(1))) void*)g,
        (__attribute__((address_space(3))) void*)l, 16, 0, 0);
}

// ---------------------------------------------------------------------------
// Index dtype detector (int64 vs int32 edge_index).
// ---------------------------------------------------------------------------
__global__ void detect_idx_kernel(const void* __restrict__ ei, int* __restrict__ flag) {
    if (blockIdx.x == 0 && threadIdx.x == 0) {
        const int* p = (const int*)ei;
        int ok = 1;
        for (int i = 0; i < 64; ++i) ok &= (p[2 * i + 1] == 0);
        *flag = ok;
    }
}
__device__ __forceinline__ long long load_idx(const void* ei, long long i, bool is64) {
    return is64 ? ((const long long*)ei)[i] : (long long)((const int*)ei)[i];
}

// ---------------------------------------------------------------------------
// CSR build (unordered groups): histogram -> atomic group-offset assignment
// -> atomic-cursor fill. No scan, no serial section. Group PLACEMENT is
// nondeterministic but membership (and thus the mean) is identical.
// ---------------------------------------------------------------------------
__global__ void hist_kernel(const void* __restrict__ ei, const int* __restrict__ flag,
                            int* __restrict__ cnt, int E) {
    const int i = blockIdx.x * blockDim.x + threadIdx.x;
    if (i >= E) return;
    const bool is64 = (*flag != 0);
    atomicAdd(&cnt[load_idx(ei, (long long)E + i, is64)], 1);
}

__global__ void offsets_kernel(const int* __restrict__ cnt, int* __restrict__ counter,
                               int* __restrict__ beg, int* __restrict__ cur, int n) {
    const int i = blockIdx.x * blockDim.x + threadIdx.x;
    if (i >= n) return;
    const int b = atomicAdd(counter, cnt[i]);
    beg[i] = b;
    cur[i] = b;
}

__global__ void fill_kernel(const void* __restrict__ ei, const int* __restrict__ flag,
                            int* __restrict__ cur, int* __restrict__ col, int E) {
    const int i = blockIdx.x * blockDim.x + threadIdx.x;
    if (i >= E) return;
    const bool is64 = (*flag != 0);
    const long long s = load_idx(ei, i, is64);
    const long long d = load_idx(ei, (long long)E + i, is64);
    col[atomicAdd(&cur[d], 1)] = (int)s;
}

// ---------------------------------------------------------------------------
// Conversions.
// ---------------------------------------------------------------------------
__global__ void convert_x_kernel(const float* __restrict__ x, unsigned short* __restrict__ xb,
                                 int N) {
    const int tid = blockIdx.x * blockDim.x + threadIdx.x;
    if (tid >= N * 40) return;
    const int row = tid / 40;
    const int c8 = (tid % 40) * 8;
    ushort8 o;
    if (c8 < IN_CH) {
        const float4 v0 = *(const float4*)(x + (size_t)row * IN_CH + c8);
        const float4 v1 = *(const float4*)(x + (size_t)row * IN_CH + c8 + 4);
        o[0] = f2bf(v0.x); o[1] = f2bf(v0.y); o[2] = f2bf(v0.z); o[3] = f2bf(v0.w);
        o[4] = f2bf(v1.x); o[5] = f2bf(v1.y); o[6] = f2bf(v1.z); o[7] = f2bf(v1.w);
    } else {
        o = (ushort8)0;
    }
    *(ushort8*)(xb + (size_t)row * 320 + c8) = o;
}

// WcatT[c][k] = (c<256 ? Wl[k][c] : Wr[k][c-256]), bf16, k >= K zero-padded.
__global__ void convert_w_kernel(const float* __restrict__ Wl, const float* __restrict__ Wr,
                                 unsigned short* __restrict__ wt, int K, int Kpad) {
    const int tid = blockIdx.x * blockDim.x + threadIdx.x;
    if (tid >= 512 * Kpad) return;
    const int c = tid / Kpad;
    const int k = tid % Kpad;
    float v = 0.f;
    if (k < K) v = (c < 256) ? Wl[(size_t)k * 256 + c] : Wr[(size_t)k * 256 + (c - 256)];
    wt[(size_t)c * Kpad + k] = f2bf(v);
}

// ---------------------------------------------------------------------------
// MFMA GEMM: [M,KPAD]bf16 x WcatT[512,KPAD]bf16 -> cols 0-255: Y bf16 (ws),
// cols 256-511: Z = . + bias (bf16 if ZBF16 else fp32).
// 128x128 tile, BK=64, 4 waves (2x2), 16x16x32 bf16 MFMA, fp32 accum.
// T2 XOR swizzle via pre-swizzled GLOBAL source + swizzled ds_read (rule #21).
// ---------------------------------------------------------------------------
template <int KPAD, bool ZBF16>
__global__ __launch_bounds__(256) void mfma_gemm_kernel(
    const unsigned short* __restrict__ A,   // [M][KPAD]
    const unsigned short* __restrict__ WT,  // [512][KPAD]
    const float* __restrict__ bias,         // [256]
    unsigned short* __restrict__ Y,         // [M][256] bf16
    void* __restrict__ Z,                   // [M][256] bf16 or fp32
    int M)
{
    __shared__ short a_lds[128 * 64];
    __shared__ short b_lds[128 * 64];

    const int lane = threadIdx.x & 63;
    const int wid  = threadIdx.x >> 6;
    const int wr = wid >> 1, wc = wid & 1;
    const int r0 = blockIdx.x * 128;
    const int c0 = blockIdx.y * 128;

    f32x4 acc[4][4];
    #pragma unroll
    for (int i = 0; i < 4; ++i)
        #pragma unroll
        for (int j = 0; j < 4; ++j) acc[i][j] = (f32x4)0.f;

    // staging: 16 wave-loads of 1024B per tile; lane l -> row = ld*8 + (l>>3),
    // source chunk = (l&7) ^ (l>>3)   [tile-row & 7 == l>>3]
    const int ldrow  = lane >> 3;
    const int schunk = (lane & 7) ^ ldrow;

    for (int kb = 0; kb < KPAD; kb += 64) {
        __syncthreads();
        #pragma unroll
        for (int j = 0; j < 4; ++j) {
            const int ld = wid * 4 + j;
            const int trow = ld * 8 + ldrow;
            const int agr = min(r0 + trow, M - 1);
            gload_lds16(A + (size_t)agr * KPAD + kb + schunk * 8,
                        (char*)a_lds + ld * 1024);
            gload_lds16(WT + (size_t)(c0 + trow) * KPAD + kb + schunk * 8,
                        (char*)b_lds + ld * 1024);
        }
        __syncthreads();

        #pragma unroll
        for (int ks = 0; ks < 2; ++ks) {
            bf16x8 af[4], bg[4];
            #pragma unroll
            for (int f = 0; f < 4; ++f) {
                const int arow = wr * 64 + f * 16 + (lane & 15);
                const int ach  = (ks * 4 + (lane >> 4)) ^ (arow & 7);
                af[f] = *(const bf16x8*)((const char*)a_lds + arow * 128 + ach * 16);
                const int brow = wc * 64 + f * 16 + (lane & 15);
                const int bch  = (ks * 4 + (lane >> 4)) ^ (brow & 7);
                bg[f] = *(const bf16x8*)((const char*)b_lds + brow * 128 + bch * 16);
            }
            #pragma unroll
            for (int fm = 0; fm < 4; ++fm)
                #pragma unroll
                for (int fn = 0; fn < 4; ++fn)
                    acc[fm][fn] = __builtin_amdgcn_mfma_f32_16x16x32_bf16(
                        af[fm], bg[fn], acc[fm][fn], 0, 0, 0);
        }
    }

    // epilogue: C/D layout col=lane&15, row=(lane>>4)*4+reg  [m89]
    const int rbase = r0 + wr * 64 + (lane >> 4) * 4;
    const int cbase = c0 + wc * 64 + (lane & 15);
    if (c0 < 256) {
        #pragma unroll
        for (int fm = 0; fm < 4; ++fm)
            #pragma unroll
            for (int fn = 0; fn < 4; ++fn) {
                const int gc = cbase + fn * 16;
                #pragma unroll
                for (int r = 0; r < 4; ++r) {
                    const int gr = rbase + fm * 16 + r;
                    if (gr < M) Y[(size_t)gr * 256 + gc] = f2bf(acc[fm][fn][r]);
                }
            }
    } else {
        #pragma unroll
        for (int fn = 0; fn < 4; ++fn) {
            const int gc = cbase + fn * 16 - 256;
            const float bv = bias[gc];
            #pragma unroll
            for (int fm = 0; fm < 4; ++fm)
                #pragma unroll
                for (int r = 0; r < 4; ++r) {
                    const int gr = rbase + fm * 16 + r;
                    if (gr < M) {
                        const float zv = acc[fm][fn][r] + bv;
                        if (ZBF16)
                            ((unsigned short*)Z)[(size_t)gr * 256 + gc] = f2bf(zv);
                        else
                            ((float*)Z)[(size_t)gr * 256 + gc] = zv;
                    }
                }
        }
    }
}

// ---------------------------------------------------------------------------
// Gather aggregation over bf16 y: out[i] = act( mean_{e}(y[col[e]]) + Z[i] ).
// LAYER1: Z bf16, act=relu, write bf16 h. else: Z fp32, write fp32 d_out.
// ---------------------------------------------------------------------------
template <bool LAYER1>
__global__ void gather_agg_kernel(const unsigned short* __restrict__ Y,
                                  const int* __restrict__ beg_arr,
                                  const int* __restrict__ cnt,
                                  const int* __restrict__ col,
                                  const void* __restrict__ Z,
                                  void* __restrict__ OUT, int N)
{
    const long long gw = ((long long)blockIdx.x * blockDim.x + threadIdx.x) >> 6;
    if (gw >= N) return;
    const int w = (int)gw;
    const int lane = threadIdx.x & 63;
    const int c4 = lane * 4;
    const int beg = beg_arr[w];
    const int deg = cnt[w];
    const int end = beg + deg;

    float4 acc = make_float4(0.f, 0.f, 0.f, 0.f);
    int e = beg;
    for (; e + 1 < end; e += 2) {
        const int s0 = col[e], s1 = col[e + 1];
        const ushort4 v0 = *(const ushort4*)(Y + (size_t)s0 * 256 + c4);
        const ushort4 v1 = *(const ushort4*)(Y + (size_t)s1 * 256 + c4);
        acc.x += bf2f(v0.x) + bf2f(v1.x);
        acc.y += bf2f(v0.y) + bf2f(v1.y);
        acc.z += bf2f(v0.z) + bf2f(v1.z);
        acc.w += bf2f(v0.w) + bf2f(v1.w);
    }
    if (e < end) {
        const ushort4 v0 = *(const ushort4*)(Y + (size_t)col[e] * 256 + c4);
        acc.x += bf2f(v0.x); acc.y += bf2f(v0.y);
        acc.z += bf2f(v0.z); acc.w += bf2f(v0.w);
    }

    const float inv = 1.0f / fmaxf((float)deg, 1.0f);
    float4 z;
    if (LAYER1) {
        const ushort4 zb = *(const ushort4*)((const unsigned short*)Z + (size_t)w * 256 + c4);
        z = make_float4(bf2f(zb.x), bf2f(zb.y), bf2f(zb.z), bf2f(zb.w));
    } else {
        z = *(const float4*)((const float*)Z + (size_t)w * 256 + c4);
    }
    float4 o;
    o.x = acc.x * inv + z.x;
    o.y = acc.y * inv + z.y;
    o.z = acc.z * inv + z.z;
    o.w = acc.w * inv + z.w;
    if (LAYER1) {
        o.x = fmaxf(o.x, 0.f); o.y = fmaxf(o.y, 0.f);
        o.z = fmaxf(o.z, 0.f); o.w = fmaxf(o.w, 0.f);
        ushort4 ob;
        ob.x = f2bf(o.x); ob.y = f2bf(o.y); ob.z = f2bf(o.z); ob.w = f2bf(o.w);
        *(ushort4*)((unsigned short*)OUT + (size_t)w * 256 + c4) = ob;
    } else {
        *(float4*)((float*)OUT + (size_t)w * 256 + c4) = o;
    }
}

// ---------------------------------------------------------------------------
extern "C" void kernel_launch(void* const* d_in, const int* in_sizes, int n_in,
                              void* d_out, int out_size, void* d_ws, size_t ws_size,
                              hipStream_t stream) {
    const float* x   = (const float*)d_in[0];
    const void*  ei  = d_in[1];
    const float* W1l = (const float*)d_in[2];
    const float* b1  = (const float*)d_in[3];
    const float* W1r = (const float*)d_in[4];
    const float* W2l = (const float*)d_in[5];
    const float* b2  = (const float*)d_in[6];
    const float* W2r = (const float*)d_in[7];

    const int N = in_sizes[0] / IN_CH;  // 100000
    const int E = in_sizes[1] / 2;      // 1000000

    char* ws = (char*)d_ws;
    size_t off = 0;
    auto alloc = [&](size_t bytes) {
        void* p = ws + off;
        off = (off + bytes + 255) & ~(size_t)255;
        return p;
    };
    int* flag    = (int*)alloc(4);
    int* cnt     = (int*)alloc((size_t)(N + 1) * 4);  // [N] counts + [1] counter
    int* counter = cnt + N;
    int* beg     = (int*)alloc((size_t)N * 4);
    int* cur     = (int*)alloc((size_t)N * 4);
    int* col     = (int*)alloc((size_t)E * 4);
    unsigned short* wt1 = (unsigned short*)alloc((size_t)512 * 320 * 2);
    unsigned short* wt2 = (unsigned short*)alloc((size_t)512 * 256 * 2);
    unsigned short* bufA = (unsigned short*)alloc((size_t)N * 320 * 2);  // x_bf16 -> h_bf16
    unsigned short* y    = (unsigned short*)alloc((size_t)N * 256 * 2);  // bf16 y

    float* out = (float*)d_out;
    unsigned short* z1 = (unsigned short*)d_out;  // layer-1 z as bf16 scratch in d_out

    // ---- CSR build (by dst, unordered groups) ----
    hipMemsetAsync(cnt, 0, (size_t)(N + 1) * 4, stream);
    detect_idx_kernel<<<1, 64, 0, stream>>>(ei, flag);
    hist_kernel<<<(E + 255) / 256, 256, 0, stream>>>(ei, flag, cnt, E);
    offsets_kernel<<<(N + 255) / 256, 256, 0, stream>>>(cnt, counter, beg, cur, N);
    fill_kernel<<<(E + 255) / 256, 256, 0, stream>>>(ei, flag, cur, col, E);

    // ---- conversions ----
    convert_x_kernel<<<(N * 40 + 255) / 256, 256, 0, stream>>>(x, bufA, N);
    convert_w_kernel<<<(512 * 320 + 255) / 256, 256, 0, stream>>>(W1l, W1r, wt1, IN_CH, 320);
    convert_w_kernel<<<(512 * 256 + 255) / 256, 256, 0, stream>>>(W2l, W2r, wt2, HID, 256);

    const dim3 ggrid((N + 127) / 128, 4);

    // ---- layer 1: y=x@W1l (bf16), z1(d_out,bf16)=x@W1r+b1 ; h(bufA)=relu(mean+z1) ----
    mfma_gemm_kernel<320, true><<<ggrid, 256, 0, stream>>>(bufA, wt1, b1, y, z1, N);
    gather_agg_kernel<true><<<(N + 3) / 4, 256, 0, stream>>>(y, beg, cnt, col, z1, bufA, N);

    // ---- layer 2: y=h@W2l, z(d_out,fp32)=h@W2r+b2 ; out = mean+z ----
    mfma_gemm_kernel<256, false><<<ggrid, 256, 0, stream>>>(bufA, wt2, b2, y, out, N);
    gather_agg_kernel<false><<<(N + 3) / 4, 256, 0, stream>>>(y, beg, cnt, col, out, out, N);
}